// Round 1
// baseline (672.258 us; speedup 1.0000x reference)
//
#include <hip/hip_runtime.h>
#include <math.h>

#define BATCH   8
#define SEQ     1024
#define DMODEL  512
#define NHEADS  8
#define DHEAD   64
#define MTOT    (BATCH*SEQ)      // 8192
#define QKVLD   (3*DMODEL)       // 1536

// ---------------------------------------------------------------------------
// SGEMM: C[M][N] = A[M][K] * B[K][N], row-major fp32.
// 128x128 block tile, BK=16, 256 threads, 8x8 microtile split as 4+4.
// Requires M%128==0, N%128==0, K%16==0 (true for all our shapes).
// ---------------------------------------------------------------------------
__global__ __launch_bounds__(256)
void sgemm128(const float* __restrict__ A, const float* __restrict__ B,
              float* __restrict__ C, int M, int N, int K)
{
    __shared__ float As[16][132];   // [k][m], transposed on store
    __shared__ float Bs[16][132];   // [k][n]

    const int t  = threadIdx.x;
    const int tx = t & 15;          // 0..15
    const int ty = t >> 4;          // 0..15
    const int bm = blockIdx.y;
    const int bn = blockIdx.x;

    const int arow = t >> 2;        // 0..63
    const int ac4  = t & 3;         // 0..3
    const int brow = t >> 5;        // 0..7
    const int bc4  = t & 31;        // 0..31

    const float* Aptr = A + (long)(bm*128 + arow)*K + ac4*4;
    const float* Bptr = B + (long)brow*N + bn*128 + bc4*4;

    float acc[8][8];
#pragma unroll
    for (int i = 0; i < 8; ++i)
#pragma unroll
        for (int j = 0; j < 8; ++j) acc[i][j] = 0.f;

    for (int kt = 0; kt < K; kt += 16) {
        float4 a0 = *(const float4*)(Aptr + kt);
        float4 a1 = *(const float4*)(Aptr + kt + 64*(long)K);
        float4 b0 = *(const float4*)(Bptr + (long)kt*N);
        float4 b1 = *(const float4*)(Bptr + (long)(kt+8)*N);

        __syncthreads();   // previous tile fully consumed
        As[ac4*4+0][arow] = a0.x;
        As[ac4*4+1][arow] = a0.y;
        As[ac4*4+2][arow] = a0.z;
        As[ac4*4+3][arow] = a0.w;
        As[ac4*4+0][arow+64] = a1.x;
        As[ac4*4+1][arow+64] = a1.y;
        As[ac4*4+2][arow+64] = a1.z;
        As[ac4*4+3][arow+64] = a1.w;
        *(float4*)&Bs[brow][bc4*4]   = b0;
        *(float4*)&Bs[brow+8][bc4*4] = b1;
        __syncthreads();

#pragma unroll
        for (int k = 0; k < 16; ++k) {
            float af[8], bf[8];
            *(float4*)&af[0] = *(const float4*)&As[k][ty*4];
            *(float4*)&af[4] = *(const float4*)&As[k][64 + ty*4];
            *(float4*)&bf[0] = *(const float4*)&Bs[k][tx*4];
            *(float4*)&bf[4] = *(const float4*)&Bs[k][64 + tx*4];
#pragma unroll
            for (int i = 0; i < 8; ++i)
#pragma unroll
                for (int j = 0; j < 8; ++j)
                    acc[i][j] = fmaf(af[i], bf[j], acc[i][j]);
        }
    }

#pragma unroll
    for (int ri = 0; ri < 2; ++ri)
#pragma unroll
    for (int i = 0; i < 4; ++i) {
        const int row = bm*128 + ri*64 + ty*4 + i;
#pragma unroll
        for (int ci = 0; ci < 2; ++ci) {
            const int col = bn*128 + ci*64 + tx*4;
            float4 v;
            v.x = acc[ri*4+i][ci*4+0];
            v.y = acc[ri*4+i][ci*4+1];
            v.z = acc[ri*4+i][ci*4+2];
            v.w = acc[ri*4+i][ci*4+3];
            *(float4*)&C[(long)row*N + col] = v;
        }
    }
}

// ---------------------------------------------------------------------------
// Fused attention, flash-style, fp32.
// Grid: (SEQ/128, BATCH*NHEADS). 256 threads.
// Per block: 128 query rows; loop over 16 KV tiles of 64 keys.
// Thread (tx=t&15, ty=t>>4): rows r = i*16+ty (i<8), score cols c = jj*16+tx
// (jj<4), output dims d = tx*4..+4.  Interleaved ownership keeps every
// ds_read_b128 at <=2-way bank aliasing (free on CDNA4).
// Output written directly in [b, n, h*64+d] layout (fp32), ready for GEMM2.
// ---------------------------------------------------------------------------
__global__ __launch_bounds__(256, 1)
void attn128(const float* __restrict__ qkv, float* __restrict__ aout,
             const float* __restrict__ temp)
{
    __shared__ float Qs[128][68];
    __shared__ float Ks[64][68];
    __shared__ float Vs[64][68];
    __shared__ float Ps[128][68];

    const int t  = threadIdx.x;
    const int tx = t & 15;
    const int ty = t >> 4;
    const int qb = blockIdx.x;        // 0..7
    const int bh = blockIdx.y;        // 0..63
    const int b  = bh >> 3;
    const int h  = bh & 7;

    const float scale = __expf(*temp);

    // ---- load Q tile (128 x 64) ----
    {
        const float* qbase = qkv + (long)(b*SEQ + qb*128)*QKVLD + h*DHEAD;
#pragma unroll
        for (int i = 0; i < 8; ++i) {
            const int idx = t + i*256;
            const int row = idx >> 4, c4 = idx & 15;
            *(float4*)&Qs[row][c4*4] = *(const float4*)(qbase + (long)row*QKVLD + c4*4);
        }
    }

    float m_[8], l_[8], o_[8][4];
#pragma unroll
    for (int i = 0; i < 8; ++i) {
        m_[i] = -1e30f; l_[i] = 0.f;
#pragma unroll
        for (int d = 0; d < 4; ++d) o_[i][d] = 0.f;
    }

    for (int jt = 0; jt < 16; ++jt) {
        __syncthreads();   // previous PV done with Ks/Vs/Ps
        // ---- load K,V tiles (64 x 64 each) ----
        {
            const float* kbase = qkv + (long)(b*SEQ + jt*64)*QKVLD + DMODEL + h*DHEAD;
            const float* vbase = kbase + DMODEL;
#pragma unroll
            for (int i = 0; i < 4; ++i) {
                const int idx = t + i*256;
                const int row = idx >> 4, c4 = idx & 15;
                *(float4*)&Ks[row][c4*4] = *(const float4*)(kbase + (long)row*QKVLD + c4*4);
                *(float4*)&Vs[row][c4*4] = *(const float4*)(vbase + (long)row*QKVLD + c4*4);
            }
        }
        __syncthreads();

        // ---- S = Q K^T (8 rows x 4 cols per thread) ----
        float s[8][4];
#pragma unroll
        for (int i = 0; i < 8; ++i)
#pragma unroll
            for (int jj = 0; jj < 4; ++jj) s[i][jj] = 0.f;

#pragma unroll 4
        for (int d4 = 0; d4 < 16; ++d4) {
            float4 kf[4];
#pragma unroll
            for (int jj = 0; jj < 4; ++jj)
                kf[jj] = *(const float4*)&Ks[jj*16 + tx][d4*4];
#pragma unroll
            for (int i = 0; i < 8; ++i) {
                const float4 qf = *(const float4*)&Qs[i*16 + ty][d4*4];
#pragma unroll
                for (int jj = 0; jj < 4; ++jj)
                    s[i][jj] += qf.x*kf[jj].x + qf.y*kf[jj].y
                              + qf.z*kf[jj].z + qf.w*kf[jj].w;
            }
        }

        // ---- online softmax update + P to LDS ----
#pragma unroll
        for (int i = 0; i < 8; ++i) {
            const int grow = qb*128 + i*16 + ty;
#pragma unroll
            for (int jj = 0; jj < 4; ++jj) {
                float sv = s[i][jj] * scale;
                const int gcol = jt*64 + jj*16 + tx;
                if (gcol == grow) sv = -1e30f;   // diagonal mask
                s[i][jj] = sv;
            }
            float tm = fmaxf(fmaxf(s[i][0], s[i][1]), fmaxf(s[i][2], s[i][3]));
            tm = fmaxf(tm, __shfl_xor(tm, 1));
            tm = fmaxf(tm, __shfl_xor(tm, 2));
            tm = fmaxf(tm, __shfl_xor(tm, 4));
            tm = fmaxf(tm, __shfl_xor(tm, 8));
            const float mn   = fmaxf(m_[i], tm);
            const float corr = __expf(m_[i] - mn);
            float ts = 0.f;
#pragma unroll
            for (int jj = 0; jj < 4; ++jj) {
                const float p = __expf(s[i][jj] - mn);
                Ps[i*16 + ty][jj*16 + tx] = p;
                ts += p;
            }
            ts += __shfl_xor(ts, 1);
            ts += __shfl_xor(ts, 2);
            ts += __shfl_xor(ts, 4);
            ts += __shfl_xor(ts, 8);
            l_[i] = l_[i]*corr + ts;
            m_[i] = mn;
#pragma unroll
            for (int d = 0; d < 4; ++d) o_[i][d] *= corr;
        }
        __syncthreads();   // P visible to everyone

        // ---- O += P V (8 rows x 4 dims per thread) ----
#pragma unroll 4
        for (int j4 = 0; j4 < 16; ++j4) {
            float4 vf[4];
#pragma unroll
            for (int jj = 0; jj < 4; ++jj)
                vf[jj] = *(const float4*)&Vs[j4*4 + jj][tx*4];
#pragma unroll
            for (int i = 0; i < 8; ++i) {
                const float4 pf = *(const float4*)&Ps[i*16 + ty][j4*4];
                o_[i][0] += pf.x*vf[0].x + pf.y*vf[1].x + pf.z*vf[2].x + pf.w*vf[3].x;
                o_[i][1] += pf.x*vf[0].y + pf.y*vf[1].y + pf.z*vf[2].y + pf.w*vf[3].y;
                o_[i][2] += pf.x*vf[0].z + pf.y*vf[1].z + pf.z*vf[2].z + pf.w*vf[3].z;
                o_[i][3] += pf.x*vf[0].w + pf.y*vf[1].w + pf.z*vf[2].w + pf.w*vf[3].w;
            }
        }
    }

    // ---- normalize + store in [b*SEQ+n][h*64+d] layout ----
#pragma unroll
    for (int i = 0; i < 8; ++i) {
        const float inv = 1.f / l_[i];
        const int row = b*SEQ + qb*128 + i*16 + ty;
        float4 v;
        v.x = o_[i][0]*inv; v.y = o_[i][1]*inv;
        v.z = o_[i][2]*inv; v.w = o_[i][3]*inv;
        *(float4*)&aout[(long)row*DMODEL + h*DHEAD + tx*4] = v;
    }
}

// ---------------------------------------------------------------------------
extern "C" void kernel_launch(void* const* d_in, const int* in_sizes, int n_in,
                              void* d_out, int out_size, void* d_ws, size_t ws_size,
                              hipStream_t stream)
{
    const float* x     = (const float*)d_in[0];   // [8,1024,512]
    const float* w_qkv = (const float*)d_in[1];   // [512,1536]
    const float* w_out = (const float*)d_in[2];   // [512,512]
    const float* temp  = (const float*)d_in[3];   // scalar (log scale)
    float* out = (float*)d_out;                   // [8,1024,512] fp32

    float* qkv  = (float*)d_ws;                       // 8192*1536 fp32 (48MB)
    float* aout = qkv + (size_t)MTOT * QKVLD;         // 8192*512  fp32 (16MB)

    // 1) qkv = x @ w_qkv
    sgemm128<<<dim3(QKVLD/128, MTOT/128), 256, 0, stream>>>(
        x, w_qkv, qkv, MTOT, QKVLD, DMODEL);

    // 2) fused masked attention, output regathered to [b,n,h*d]
    attn128<<<dim3(SEQ/128, BATCH*NHEADS), 256, 0, stream>>>(qkv, aout, temp);

    // 3) out = aout @ w_out
    sgemm128<<<dim3(DMODEL/128, MTOT/128), 256, 0, stream>>>(
        aout, w_out, out, MTOT, DMODEL, DMODEL);
}

// Round 2
// 179.807 us; speedup vs baseline: 3.7388x; 3.7388x over previous
//
#include <hip/hip_runtime.h>
#include <math.h>

#define BATCH  8
#define SEQ    1024
#define DMODEL 512
#define NHEADS 8
#define DHEAD  64
#define MTOT   (BATCH*SEQ)      // 8192
#define QKVLD  (3*DMODEL)       // 1536

typedef unsigned short ushortT;
typedef __attribute__((ext_vector_type(8))) short short8;
typedef __attribute__((ext_vector_type(4))) float f32x4;

typedef __attribute__((address_space(3))) unsigned char lds_byte;
typedef __attribute__((address_space(1))) const unsigned char glob_byte;

__device__ inline void g2l16(const void* g, void* l) {
    __builtin_amdgcn_global_load_lds((glob_byte*)g, (lds_byte*)l, 16, 0, 0);
}

__device__ inline ushortT f2bf(float f) {
    union { float f; unsigned u; } v; v.f = f;
    unsigned r = (v.u + 0x7FFFu + ((v.u >> 16) & 1u)) >> 16;
    return (ushortT)r;
}

// ---------------------------------------------------------------------------
// Elementwise fp32 -> bf16 (8 elems / thread)
// ---------------------------------------------------------------------------
__global__ __launch_bounds__(256)
void cvt_bf16(const float* __restrict__ in, ushortT* __restrict__ out, int n8)
{
    int gid = blockIdx.x * 256 + threadIdx.x;
    if (gid >= n8) return;
    const float4 a = *(const float4*)(in + (long)gid*8);
    const float4 b = *(const float4*)(in + (long)gid*8 + 4);
    ushortT o[8];
    o[0]=f2bf(a.x); o[1]=f2bf(a.y); o[2]=f2bf(a.z); o[3]=f2bf(a.w);
    o[4]=f2bf(b.x); o[5]=f2bf(b.y); o[6]=f2bf(b.z); o[7]=f2bf(b.w);
    *(short8*)(out + (long)gid*8) = *(short8*)o;
}

// ---------------------------------------------------------------------------
// W [K][N] fp32 -> WT [N][K] bf16  (32x32 LDS tiles)
// ---------------------------------------------------------------------------
__global__ __launch_bounds__(256)
void cvt_transpose(const float* __restrict__ W, ushortT* __restrict__ WT,
                   int K, int N)
{
    __shared__ float T[32][33];
    const int t = threadIdx.x;
    const int n0 = blockIdx.x * 32;
    const int k0 = blockIdx.y * 32;
    {
        const int r = t >> 3, c4 = (t & 7) * 4;
        const float4 v = *(const float4*)(W + (long)(k0 + r)*N + n0 + c4);
        T[c4+0][r] = v.x; T[c4+1][r] = v.y; T[c4+2][r] = v.z; T[c4+3][r] = v.w;
    }
    __syncthreads();
    {
        const int n = t >> 3, k4 = (t & 7) * 4;
        ushortT o[4];
        o[0] = f2bf(T[n][k4+0]); o[1] = f2bf(T[n][k4+1]);
        o[2] = f2bf(T[n][k4+2]); o[3] = f2bf(T[n][k4+3]);
        *(uint2*)(WT + (long)(n0 + n)*K + k0 + k4) = *(uint2*)o;
    }
}

// ---------------------------------------------------------------------------
// bf16 MFMA GEMM: C[M][N] = A[M][K] * BT[N][K]^T
// 128x128 tile, BK=32, 256 thr (2x2 waves, 64x64 each), global_load_lds,
// XOR swizzle slot^((row>>1)&3) applied on the GLOBAL source (linear LDS
// dest) and on the ds_read side (rule 21).
// ---------------------------------------------------------------------------
template <int OUT_BF16>
__global__ __launch_bounds__(256, 2)
void gemm_bf16(const ushortT* __restrict__ A, const ushortT* __restrict__ BT,
               void* __restrict__ Cv, int M, int N, int K)
{
    __shared__ ushortT As[128*32];
    __shared__ ushortT Bs[128*32];

    const int t    = threadIdx.x;
    const int lane = t & 63;
    const int w    = t >> 6;
    const int l15  = lane & 15, l4 = lane >> 4;
    const int bm   = blockIdx.y, bn = blockIdx.x;

    const int srow = t >> 2;     // 0..63
    const int slot = t & 3;

    f32x4 acc[4][4] = {};

    for (int kt = 0; kt < K; kt += 32) {
#pragma unroll
        for (int c = 0; c < 2; ++c) {
            const int row  = c*64 + srow;
            const int scol = ((slot ^ ((row >> 1) & 3)) << 4);   // bytes
            g2l16((const char*)(A  + (long)(bm*128 + row)*K + kt) + scol,
                  (char*)As + c*4096 + t*16);
            g2l16((const char*)(BT + (long)(bn*128 + row)*K + kt) + scol,
                  (char*)Bs + c*4096 + t*16);
        }
        asm volatile("s_waitcnt vmcnt(0)" ::: "memory");
        __syncthreads();

        short8 a[4], b[4];
#pragma unroll
        for (int i = 0; i < 4; ++i) {
            const int ra = (w >> 1)*64 + i*16 + l15;
            const int ca = (l4*8) ^ (((ra >> 1) & 3) << 3);
            a[i] = *(const short8*)&As[ra*32 + ca];
            const int rb = (w & 1)*64 + i*16 + l15;
            const int cb = (l4*8) ^ (((rb >> 1) & 3) << 3);
            b[i] = *(const short8*)&Bs[rb*32 + cb];
        }
#pragma unroll
        for (int i = 0; i < 4; ++i)
#pragma unroll
            for (int j = 0; j < 4; ++j)
                acc[i][j] = __builtin_amdgcn_mfma_f32_16x16x32_bf16(
                                a[i], b[j], acc[i][j], 0, 0, 0);
        __syncthreads();
    }

#pragma unroll
    for (int i = 0; i < 4; ++i) {
        const int row0 = bm*128 + (w >> 1)*64 + i*16 + l4*4;
#pragma unroll
        for (int j = 0; j < 4; ++j) {
            const int col = bn*128 + (w & 1)*64 + j*16 + l15;
#pragma unroll
            for (int r = 0; r < 4; ++r) {
                const float v = acc[i][j][r];
                if (OUT_BF16) ((ushortT*)Cv)[(long)(row0 + r)*N + col] = f2bf(v);
                else          ((float*)Cv)[(long)(row0 + r)*N + col]   = v;
            }
        }
    }
}

// ---------------------------------------------------------------------------
// Fused flash attention, bf16 MFMA, diag mask.
// Grid (8 qtiles, 64 bh), 256 thr = 4 waves x 32 q-rows.
// LDS tiles [rows][64] bf16, elem-XOR swizzle col ^ ((row&7)<<3).
// Q/K staged via global_load_lds with pre-swizzled global source; V
// transposed during reg staging (scalar writes); P via swizzled LDS.
// ---------------------------------------------------------------------------
__global__ __launch_bounds__(256, 2)
void attn_mfma(const ushortT* __restrict__ qkv, ushortT* __restrict__ aout,
               const float* __restrict__ temp)
{
    __shared__ ushortT Qs[128*64];
    __shared__ ushortT Ks[64*64];
    __shared__ ushortT Vt[64*64];   // [d][key]
    __shared__ ushortT Ps[128*64];

    const int t    = threadIdx.x;
    const int lane = t & 63;
    const int w    = t >> 6;
    const int l15  = lane & 15, l4 = lane >> 4;
    const int qb   = blockIdx.x;
    const int b    = blockIdx.y >> 3, h = blockIdx.y & 7;

    const float scale = __expf(temp[0]);
    const long  row0  = (long)b * SEQ * QKVLD;

    // ---- stage Q (128x64, 4 calls) ----
    {
        const char* qbase = (const char*)(qkv + row0 + (long)qb*128*QKVLD + h*DHEAD);
#pragma unroll
        for (int c = 0; c < 4; ++c) {
            const int row  = c*32 + (t >> 3);
            const int scol = ((t & 7) ^ (row & 7)) << 4;
            g2l16(qbase + (long)row*(QKVLD*2) + scol, (char*)Qs + c*4096 + t*16);
        }
    }

    float m_[2][4], l_[2][4];
    f32x4 o_[2][4] = {};
#pragma unroll
    for (int i = 0; i < 2; ++i)
#pragma unroll
        for (int r = 0; r < 4; ++r) { m_[i][r] = -1e30f; l_[i][r] = 0.f; }

    for (int jt = 0; jt < 16; ++jt) {
        __syncthreads();   // prev PV done with Ks/Vt/Ps

        // ---- stage K (64x64, 2 calls) ----
        {
            const char* kbase = (const char*)(qkv + row0 + (long)jt*64*QKVLD
                                              + DMODEL + h*DHEAD);
#pragma unroll
            for (int c = 0; c < 2; ++c) {
                const int row  = c*32 + (t >> 3);
                const int scol = ((t & 7) ^ (row & 7)) << 4;
                g2l16(kbase + (long)row*(QKVLD*2) + scol, (char*)Ks + c*4096 + t*16);
            }
        }
        // ---- stage V transposed: thread = 1 key x 16 d ----
        {
            const ushortT* vbase = qkv + row0 + (long)jt*64*QKVLD + 2*DMODEL + h*DHEAD;
            const int key = t >> 2, d0 = (t & 3) * 16;
            ushortT vv[16];
            *(short8*)&vv[0] = *(const short8*)(vbase + (long)key*QKVLD + d0);
            *(short8*)&vv[8] = *(const short8*)(vbase + (long)key*QKVLD + d0 + 8);
#pragma unroll
            for (int e = 0; e < 16; ++e) {
                const int row = d0 + e;
                Vt[row*64 + (key ^ ((row & 7) << 3))] = vv[e];
            }
        }
        asm volatile("s_waitcnt vmcnt(0)" ::: "memory");
        __syncthreads();

        // ---- S = Q K^T (per wave: 32 rows x 64 keys) ----
        f32x4 s_[2][4] = {};
#pragma unroll
        for (int kk = 0; kk < 2; ++kk) {
            short8 qa[2], kb[4];
#pragma unroll
            for (int i = 0; i < 2; ++i) {
                const int r = w*32 + i*16 + l15;
                const int c = (kk*32 + l4*8) ^ ((r & 7) << 3);
                qa[i] = *(const short8*)&Qs[r*64 + c];
            }
#pragma unroll
            for (int j = 0; j < 4; ++j) {
                const int r = j*16 + l15;
                const int c = (kk*32 + l4*8) ^ ((r & 7) << 3);
                kb[j] = *(const short8*)&Ks[r*64 + c];
            }
#pragma unroll
            for (int i = 0; i < 2; ++i)
#pragma unroll
                for (int j = 0; j < 4; ++j)
                    s_[i][j] = __builtin_amdgcn_mfma_f32_16x16x32_bf16(
                                   qa[i], kb[j], s_[i][j], 0, 0, 0);
        }

        // ---- online softmax (rows owned via C-layout) ----
#pragma unroll
        for (int i = 0; i < 2; ++i) {
#pragma unroll
            for (int r = 0; r < 4; ++r) {
                const int lrow = w*32 + i*16 + l4*4 + r;
                const int grow = qb*128 + lrow;
                float sv[4];
#pragma unroll
                for (int j = 0; j < 4; ++j) {
                    const float x = s_[i][j][r] * scale;
                    const int gcol = jt*64 + j*16 + l15;
                    sv[j] = (gcol == grow) ? -1e30f : x;
                }
                float mx = fmaxf(fmaxf(sv[0], sv[1]), fmaxf(sv[2], sv[3]));
                mx = fmaxf(mx, __shfl_xor(mx, 1));
                mx = fmaxf(mx, __shfl_xor(mx, 2));
                mx = fmaxf(mx, __shfl_xor(mx, 4));
                mx = fmaxf(mx, __shfl_xor(mx, 8));
                const float mn   = fmaxf(m_[i][r], mx);
                const float corr = __expf(m_[i][r] - mn);
                m_[i][r] = mn;
                float ts = 0.f;
#pragma unroll
                for (int j = 0; j < 4; ++j) {
                    const float p = __expf(sv[j] - mn);
                    ts += p;
                    Ps[lrow*64 + ((j*16 + l15) ^ ((lrow & 7) << 3))] = f2bf(p);
                }
                ts += __shfl_xor(ts, 1);
                ts += __shfl_xor(ts, 2);
                ts += __shfl_xor(ts, 4);
                ts += __shfl_xor(ts, 8);
                l_[i][r] = l_[i][r] * corr + ts;
#pragma unroll
                for (int j = 0; j < 4; ++j) o_[i][j][r] *= corr;
            }
        }
        __syncthreads();   // Ps visible

        // ---- O += P V ----
#pragma unroll
        for (int kk = 0; kk < 2; ++kk) {
            short8 pa[2], vb[4];
#pragma unroll
            for (int i = 0; i < 2; ++i) {
                const int r = w*32 + i*16 + l15;
                const int c = (kk*32 + l4*8) ^ ((r & 7) << 3);
                pa[i] = *(const short8*)&Ps[r*64 + c];
            }
#pragma unroll
            for (int j = 0; j < 4; ++j) {
                const int r = j*16 + l15;
                const int c = (kk*32 + l4*8) ^ ((r & 7) << 3);
                vb[j] = *(const short8*)&Vt[r*64 + c];
            }
#pragma unroll
            for (int i = 0; i < 2; ++i)
#pragma unroll
                for (int j = 0; j < 4; ++j)
                    o_[i][j] = __builtin_amdgcn_mfma_f32_16x16x32_bf16(
                                   pa[i], vb[j], o_[i][j], 0, 0, 0);
        }
    }

    // ---- normalize + store bf16 [b*SEQ+n][h*64+d] ----
#pragma unroll
    for (int i = 0; i < 2; ++i) {
#pragma unroll
        for (int r = 0; r < 4; ++r) {
            const float inv  = 1.0f / l_[i][r];
            const long  grow = (long)b*SEQ + qb*128 + w*32 + i*16 + l4*4 + r;
#pragma unroll
            for (int j = 0; j < 4; ++j)
                aout[grow*DMODEL + h*DHEAD + j*16 + l15] = f2bf(o_[i][j][r] * inv);
        }
    }
}

// ---------------------------------------------------------------------------
extern "C" void kernel_launch(void* const* d_in, const int* in_sizes, int n_in,
                              void* d_out, int out_size, void* d_ws, size_t ws_size,
                              hipStream_t stream)
{
    const float* x     = (const float*)d_in[0];   // [8192,512]
    const float* w_qkv = (const float*)d_in[1];   // [512,1536]
    const float* w_out = (const float*)d_in[2];   // [512,512]
    const float* temp  = (const float*)d_in[3];
    float* out = (float*)d_out;

    char* ws = (char*)d_ws;
    ushortT* x_bf   = (ushortT*)(ws);                          //  8 MB
    ushortT* wqkvT  = (ushortT*)(ws + 8388608);                //  1.5 MB
    ushortT* woutT  = (ushortT*)(ws + 9961472);                //  0.5 MB
    ushortT* qkv_bf = (ushortT*)(ws + 10485760);               // 24 MB
    ushortT* aout   = (ushortT*)(ws + 35651584);               //  8 MB

    // converts
    cvt_bf16<<<dim3((MTOT*DMODEL/8)/256), 256, 0, stream>>>(x, x_bf, MTOT*DMODEL/8);
    cvt_transpose<<<dim3(QKVLD/32, DMODEL/32), 256, 0, stream>>>(w_qkv, wqkvT, DMODEL, QKVLD);
    cvt_transpose<<<dim3(DMODEL/32, DMODEL/32), 256, 0, stream>>>(w_out, woutT, DMODEL, DMODEL);

    // qkv = x @ w_qkv   (bf16 out)
    gemm_bf16<1><<<dim3(QKVLD/128, MTOT/128), 256, 0, stream>>>(
        x_bf, wqkvT, qkv_bf, MTOT, QKVLD, DMODEL);

    // fused attention -> aout bf16 [8192][512]
    attn_mfma<<<dim3(SEQ/128, BATCH*NHEADS), 256, 0, stream>>>(qkv_bf, aout, temp);

    // out = aout @ w_out  (fp32 out)
    gemm_bf16<0><<<dim3(DMODEL/128, MTOT/128), 256, 0, stream>>>(
        aout, woutT, out, MTOT, DMODEL, DMODEL);
}